// Round 11
// baseline (157.186 us; speedup 1.0000x reference)
//
#include <hip/hip_runtime.h>

#define NB 16384
#define FEATC 106496
#define RNG (FEATC/8)
#define QSCALE (1.0f/2048.0f)
#define QINV   2048.0f

typedef float f32x4 __attribute__((ext_vector_type(4)));

#define SB() __builtin_amdgcn_sched_barrier(0)

__device__ __forceinline__ float cre(float x){
    float c = fminf(fmaxf(x, 0.0f), 127.0f/128.0f);
    return c + 0.1f*(x-c);
}

// ---------------- K0: per-expert sample lists (parallel 2-pass, 32 blocks) ----
__global__ __launch_bounds__(256) void k0_group(
    const int* __restrict__ wm, int* __restrict__ list, int* __restrict__ cnt)
{
    __shared__ int pref[256];
    const int e = blockIdx.x;
    const int t = threadIdx.x;
    int c = 0;
    #pragma unroll 8
    for (int i = t; i < NB; i += 256) c += (wm[i] == e) ? 1 : 0;
    pref[t] = c;
    __syncthreads();
    for (int d = 1; d < 256; d <<= 1){
        int v = (t >= d) ? pref[t-d] : 0;
        __syncthreads();
        pref[t] += v;
        __syncthreads();
    }
    const int total = pref[255];
    int pos = pref[t] - c;
    for (int i = t; i < NB; i += 256){
        if (wm[i] == e){
            if (pos < 1024) list[e*1024 + pos] = i;
            pos++;
        }
    }
    if (t == 255) cnt[e] = total > 1024 ? 1024 : total;
}

// ---------------- K1: fp32 -> biased... no: plain int8 row-major (round-10) ----
__global__ __launch_bounds__(256) void convert_i8(
    const float* __restrict__ src, unsigned int* __restrict__ dst, int n4)
{
    int i = blockIdx.x*blockDim.x + threadIdx.x;
    const int stride = gridDim.x*blockDim.x;
    for (; i < n4; i += stride){
        const f32x4* sp = reinterpret_cast<const f32x4*>(src) + i;
        f32x4 v = __builtin_nontemporal_load(sp);
        int a = __float2int_rn(fminf(fmaxf(v.x*QINV, -127.0f), 127.0f)) + 128;
        int b = __float2int_rn(fminf(fmaxf(v.y*QINV, -127.0f), 127.0f)) + 128;
        int c = __float2int_rn(fminf(fmaxf(v.z*QINV, -127.0f), 127.0f)) + 128;
        int d = __float2int_rn(fminf(fmaxf(v.w*QINV, -127.0f), 127.0f)) + 128;
        dst[i] = (unsigned)a | ((unsigned)b << 8) | ((unsigned)c << 16) | ((unsigned)d << 24);
    }
}

// ---------------- K2: row-range XCD-pinned gather, packed u32 atomics ----
// block 512 thr = 8 waves; wave = (sample b, range k). Table rows 256B, layout unchanged.
__global__ __launch_bounds__(512, 8) void k2_range(
    const int* __restrict__ indices, const int* __restrict__ offsets,
    const unsigned char* __restrict__ tab, unsigned int* __restrict__ pk)
{
    const int tid = threadIdx.x;
    const int l  = tid & 63;
    const int wv = tid >> 6;
    const int k  = blockIdx.x & 7;                 // range == XCD (round-robin dispatch)
    const int b  = (blockIdx.x >> 3)*8 + wv;

    const int base = __builtin_amdgcn_readfirstlane(offsets[b]);
    const int vrow = indices[base + (l & 31)];     // lane j<32 holds row_j
    const int rlo  = k * RNG;
    const unsigned rr = (unsigned)(vrow - rlo);
    unsigned msk = (unsigned)__ballot(rr < (unsigned)RNG);  // low 32 bits = lanes 0..31
    if (msk == 0u) return;

    // branchless extraction of up to 8 matching rows (uniform scalar mask walk)
    unsigned m2 = msk;
    int  r0,r1,r2,r3,r4,r5,r6,r7;
    bool u0,u1,u2,u3,u4,u5,u6,u7;
    #define EXTRACT(rt, ut)                                              \
        {  const bool have = (m2 != 0u);                                 \
           const int j = (int)__builtin_ctz(m2 | 0x80000000u);           \
           const int rs = __shfl(vrow, j);                               \
           rt = have ? rs : rlo;  ut = have;                             \
           m2 = have ? (m2 & (m2 - 1u)) : 0u; }
    EXTRACT(r0,u0) EXTRACT(r1,u1) EXTRACT(r2,u2) EXTRACT(r3,u3)
    EXTRACT(r4,u4) EXTRACT(r5,u5) EXTRACT(r6,u6) EXTRACT(r7,u7)
    #undef EXTRACT

    unsigned w0 = *reinterpret_cast<const unsigned int*>(tab + (size_t)r0*256 + l*4);
    unsigned w1 = *reinterpret_cast<const unsigned int*>(tab + (size_t)r1*256 + l*4);
    unsigned w2 = *reinterpret_cast<const unsigned int*>(tab + (size_t)r2*256 + l*4);
    unsigned w3 = *reinterpret_cast<const unsigned int*>(tab + (size_t)r3*256 + l*4);
    unsigned w4 = *reinterpret_cast<const unsigned int*>(tab + (size_t)r4*256 + l*4);
    unsigned w5 = *reinterpret_cast<const unsigned int*>(tab + (size_t)r5*256 + l*4);
    unsigned w6 = *reinterpret_cast<const unsigned int*>(tab + (size_t)r6*256 + l*4);
    unsigned w7 = *reinterpret_cast<const unsigned int*>(tab + (size_t)r7*256 + l*4);

    unsigned aL = 0, aH = 0;
    #define ACCUM(wt, ut)                                   \
        {  const unsigned x = ut ? wt : 0u;                 \
           aL += x & 0x00FF00FFu;                           \
           aH += (x >> 8) & 0x00FF00FFu; }
    ACCUM(w0,u0) ACCUM(w1,u1) ACCUM(w2,u2) ACCUM(w3,u3)
    ACCUM(w4,u4) ACCUM(w5,u5) ACCUM(w6,u6) ACCUM(w7,u7)
    #undef ACCUM

    // rare: >8 rows in this range
    while (m2){
        const int j = (int)__builtin_ctz(m2); m2 &= m2 - 1u;
        const int row = __shfl(vrow, j);
        const unsigned x = *reinterpret_cast<const unsigned int*>(tab + (size_t)row*256 + l*4);
        aL += x & 0x00FF00FFu;
        aH += (x >> 8) & 0x00FF00FFu;
    }

    unsigned int* p = pk + (size_t)b*128 + 2*l;
    atomicAdd(p,     aL);
    atomicAdd(p + 1, aH);
}

// ---------------- K3: expert-grouped MLP tail, packed accum input ----
__global__ __launch_bounds__(256, 2) void k3_tail(
    const int* __restrict__ list, const int* __restrict__ cnt,
    const unsigned int* __restrict__ pk, const float* __restrict__ mbias,
    const float* __restrict__ vW1, const float* __restrict__ vb1,
    const float* __restrict__ vW2, const float* __restrict__ vb2,
    const float* __restrict__ vW3, const float* __restrict__ vb3,
    const float* __restrict__ pfW, const float* __restrict__ pfb,
    const float* __restrict__ ptW, const float* __restrict__ ptb,
    float* __restrict__ out0, float* __restrict__ out1, float* __restrict__ out2)
{
    const int tid = threadIdx.x;
    const int l  = tid & 63;
    const int wv = tid >> 6;
    const int e     = blockIdx.x >> 5;
    const int chunk = blockIdx.x & 31;
    const int n     = cnt[e];
    const int idx0  = chunk*32 + wv*8;
    if (idx0 >= n) return;
    const int g = e >> 3;

    const float4 mb = *reinterpret_cast<const float4*>(mbias + l*4);

    float4 w[8], w2r[8];
    {
        const float* w1p = vW1 + e*4096;
        #pragma unroll
        for (int k=0;k<8;k++) w[k]   = *reinterpret_cast<const float4*>(w1p + k*256 + l*4);
        #pragma unroll
        for (int k=0;k<8;k++) w2r[k] = *reinterpret_cast<const float4*>(w1p + (8+k)*256 + l*4);
    }
    const float4 w2a = *reinterpret_cast<const float4*>(vW2 + e*512 + l*4);
    const float4 w2b = *reinterpret_cast<const float4*>(vW2 + e*512 + 256 + l*4);
    float4 wf[4], wt[4];
    #pragma unroll
    for (int k=0;k<4;k++){
        wf[k] = *reinterpret_cast<const float4*>(pfW + e*1024 + k*256 + l*4);
        wt[k] = *reinterpret_cast<const float4*>(ptW + e*1024 + k*256 + l*4);
    }
    const float b1l = vb1[e*16 + (l&15)];
    const int   o2  = ((l&1)<<4) + (l>>2);
    const float b2l = vb2[e*32 + o2];
    const float b3  = vb3[e];
    const int   oo  = ((l&3)<<4) + (l>>2);
    const float pfbl = pfb[e*64 + oo];
    const float ptbl = ptb[e*64 + oo];
    const int   i32 = l & 31;
    const float w3l = vW3[e*32 + i32];
    const int   srcl = (i32 < 16) ? (4*i32) : (4*(i32-16)+1);
    const int   sf = 4 + 4*g + (l&3);
    const int   st = sf + 16;

    const int nrem = (n - idx0) < 8 ? (n - idx0) : 8;
    int bcur = __builtin_amdgcn_readfirstlane(list[e*1024 + idx0]);
    uint2 ucur = *reinterpret_cast<const uint2*>(pk + (size_t)bcur*128 + 2*l);

    for (int s = 0; s < nrem; ++s){
        int bnext = bcur; uint2 unext = ucur;
        if (s+1 < nrem){
            bnext = __builtin_amdgcn_readfirstlane(list[e*1024 + idx0 + s + 1]);
            unext = *reinterpret_cast<const uint2*>(pk + (size_t)bnext*128 + 2*l);
        }
        float4 acc;
        acc.x = (float)((int)(ucur.x & 0xFFFFu) - 4096) * QSCALE + mb.x;
        acc.y = (float)((int)(ucur.y & 0xFFFFu) - 4096) * QSCALE + mb.y;
        acc.z = (float)((int)(ucur.x >> 16)     - 4096) * QSCALE + mb.z;
        acc.w = (float)((int)(ucur.y >> 16)     - 4096) * QSCALE + mb.w;

        const float psqt = __shfl(acc.x, 0);
        float4 embv;
        embv.x = cre(acc.x); embv.y = cre(acc.y); embv.z = cre(acc.z); embv.w = cre(acc.w);

        float a1[16];
        #pragma unroll
        for (int k=0;k<8;k++)
            a1[k]   = w[k].x*embv.x + w[k].y*embv.y + w[k].z*embv.z + w[k].w*embv.w;
        #pragma unroll
        for (int k=0;k<8;k++)
            a1[8+k] = w2r[k].x*embv.x + w2r[k].y*embv.y + w2r[k].z*embv.z + w2r[k].w*embv.w;
        #pragma unroll
        for (int i=0;i<8;i++){
            float give = (l&1) ? a1[2*i] : a1[2*i+1];
            float keep = (l&1) ? a1[2*i+1] : a1[2*i];
            a1[i] = keep + __shfl_xor(give, 1);
        }
        #pragma unroll
        for (int i=0;i<4;i++){
            float give = ((l>>1)&1) ? a1[2*i] : a1[2*i+1];
            float keep = ((l>>1)&1) ? a1[2*i+1] : a1[2*i];
            a1[i] = keep + __shfl_xor(give, 2);
        }
        #pragma unroll
        for (int i=0;i<2;i++){
            float give = ((l>>2)&1) ? a1[2*i] : a1[2*i+1];
            float keep = ((l>>2)&1) ? a1[2*i+1] : a1[2*i];
            a1[i] = keep + __shfl_xor(give, 4);
        }
        {
            float give = ((l>>3)&1) ? a1[0] : a1[1];
            float keep = ((l>>3)&1) ? a1[1] : a1[0];
            a1[0] = keep + __shfl_xor(give, 8);
        }
        a1[0] += __shfl_xor(a1[0], 16);
        a1[0] += __shfl_xor(a1[0], 32);
        const float h1v = cre(a1[0] + b1l);

        float4 xh1;
        xh1.x = __shfl(h1v, (l&3)*4 + 0);
        xh1.y = __shfl(h1v, (l&3)*4 + 1);
        xh1.z = __shfl(h1v, (l&3)*4 + 2);
        xh1.w = __shfl(h1v, (l&3)*4 + 3);
        float a20 = w2a.x*xh1.x + w2a.y*xh1.y + w2a.z*xh1.z + w2a.w*xh1.w;
        float a21 = w2b.x*xh1.x + w2b.y*xh1.y + w2b.z*xh1.z + w2b.w*xh1.w;
        float v2;
        {
            float give = (l&1) ? a20 : a21;
            float keep = (l&1) ? a21 : a20;
            v2 = keep + __shfl_xor(give, 1);
            v2 += __shfl_xor(v2, 2);
        }
        const float h2v = cre(v2 + b2l);

        const float h2full = __shfl(h2v, srcl);
        float pv = w3l * h2full;
        pv += __shfl_xor(pv, 1); pv += __shfl_xor(pv, 2); pv += __shfl_xor(pv, 4);
        pv += __shfl_xor(pv, 8); pv += __shfl_xor(pv, 16);
        if (l == 0) out0[bcur] = tanhf(pv + b3 + psqt);

        float4 xpf, xpt;
        xpf.x = __shfl(embv.x, sf); xpf.y = __shfl(embv.y, sf);
        xpf.z = __shfl(embv.z, sf); xpf.w = __shfl(embv.w, sf);
        xpt.x = __shfl(embv.x, st); xpt.y = __shfl(embv.y, st);
        xpt.z = __shfl(embv.z, st); xpt.w = __shfl(embv.w, st);
        float apf[4], apt[4];
        #pragma unroll
        for (int k=0;k<4;k++){
            apf[k] = wf[k].x*xpf.x + wf[k].y*xpf.y + wf[k].z*xpf.z + wf[k].w*xpf.w;
            apt[k] = wt[k].x*xpt.x + wt[k].y*xpt.y + wt[k].z*xpt.z + wt[k].w*xpt.w;
        }
        #pragma unroll
        for (int i=0;i<2;i++){
            float give = (l&1) ? apf[2*i] : apf[2*i+1];
            float keep = (l&1) ? apf[2*i+1] : apf[2*i];
            apf[i] = keep + __shfl_xor(give, 1);
            give = (l&1) ? apt[2*i] : apt[2*i+1];
            keep = (l&1) ? apt[2*i+1] : apt[2*i];
            apt[i] = keep + __shfl_xor(give, 1);
        }
        float pfv, ptv;
        {
            float give = ((l>>1)&1) ? apf[0] : apf[1];
            float keep = ((l>>1)&1) ? apf[1] : apf[0];
            pfv = keep + __shfl_xor(give, 2);
            give = ((l>>1)&1) ? apt[0] : apt[1];
            keep = ((l>>1)&1) ? apt[1] : apt[0];
            ptv = keep + __shfl_xor(give, 2);
        }
        out1[bcur*64 + oo] = pfv + pfbl;
        out2[bcur*64 + oo] = ptv + ptbl;

        bcur = bnext; ucur = unext;
    }
}

// ---------------- fallback: direct fp32 monolithic ----------------
__global__ __launch_bounds__(256, 4) void nnue_fused_f(
    const int* __restrict__ indices,
    const int* __restrict__ offsets,
    const int* __restrict__ which_model,
    const float* __restrict__ embed,
    const float* __restrict__ main_bias,
    const float* __restrict__ vW1, const float* __restrict__ vb1,
    const float* __restrict__ vW2, const float* __restrict__ vb2,
    const float* __restrict__ vW3, const float* __restrict__ vb3,
    const float* __restrict__ pfW, const float* __restrict__ pfb,
    const float* __restrict__ ptW, const float* __restrict__ ptb,
    float* __restrict__ out0, float* __restrict__ out1, float* __restrict__ out2)
{
    const int tid = threadIdx.x;
    const int l  = tid & 63;
    const int wv = tid >> 6;
    const int b  = (blockIdx.x << 2) + wv;
    const int e    = __builtin_amdgcn_readfirstlane(which_model[b]);
    const int base = __builtin_amdgcn_readfirstlane(offsets[b]);
    const int g    = e >> 3;

    float4 acc = *reinterpret_cast<const float4*>(main_bias + l*4);
    for (int k=0;k<32;k++){
        const int row = indices[base + k];
        const float4 v = *reinterpret_cast<const float4*>(embed + (size_t)row*256 + l*4);
        acc.x += v.x; acc.y += v.y; acc.z += v.z; acc.w += v.w;
    }
    const float psqt = __shfl(acc.x, 0);
    float4 embv;
    embv.x = cre(acc.x); embv.y = cre(acc.y); embv.z = cre(acc.z); embv.w = cre(acc.w);

    float a1[16];
    {
        const float* w1 = vW1 + e*4096;
        #pragma unroll
        for (int k=0;k<16;k++){
            const float4 ww = *reinterpret_cast<const float4*>(w1 + k*256 + l*4);
            a1[k] = ww.x*embv.x + ww.y*embv.y + ww.z*embv.z + ww.w*embv.w;
        }
    }
    #pragma unroll
    for (int i=0;i<8;i++){
        float give = (l&1) ? a1[2*i] : a1[2*i+1];
        float keep = (l&1) ? a1[2*i+1] : a1[2*i];
        a1[i] = keep + __shfl_xor(give, 1);
    }
    #pragma unroll
    for (int i=0;i<4;i++){
        float give = ((l>>1)&1) ? a1[2*i] : a1[2*i+1];
        float keep = ((l>>1)&1) ? a1[2*i+1] : a1[2*i];
        a1[i] = keep + __shfl_xor(give, 2);
    }
    #pragma unroll
    for (int i=0;i<2;i++){
        float give = ((l>>2)&1) ? a1[2*i] : a1[2*i+1];
        float keep = ((l>>2)&1) ? a1[2*i+1] : a1[2*i];
        a1[i] = keep + __shfl_xor(give, 4);
    }
    {
        float give = ((l>>3)&1) ? a1[0] : a1[1];
        float keep = ((l>>3)&1) ? a1[1] : a1[0];
        a1[0] = keep + __shfl_xor(give, 8);
    }
    a1[0] += __shfl_xor(a1[0], 16);
    a1[0] += __shfl_xor(a1[0], 32);
    const float h1v = cre(a1[0] + vb1[e*16 + (l&15)]);

    float4 xh1;
    xh1.x = __shfl(h1v, (l&3)*4 + 0);
    xh1.y = __shfl(h1v, (l&3)*4 + 1);
    xh1.z = __shfl(h1v, (l&3)*4 + 2);
    xh1.w = __shfl(h1v, (l&3)*4 + 3);
    const float4 w2a = *reinterpret_cast<const float4*>(vW2 + e*512 + l*4);
    const float4 w2b = *reinterpret_cast<const float4*>(vW2 + e*512 + 256 + l*4);
    float a20 = w2a.x*xh1.x + w2a.y*xh1.y + w2a.z*xh1.z + w2a.w*xh1.w;
    float a21 = w2b.x*xh1.x + w2b.y*xh1.y + w2b.z*xh1.z + w2b.w*xh1.w;
    float v2;
    {
        float give = (l&1) ? a20 : a21;
        float keep = (l&1) ? a21 : a20;
        v2 = keep + __shfl_xor(give, 1);
        v2 += __shfl_xor(v2, 2);
    }
    const int o2 = ((l&1)<<4) + (l>>2);
    const float h2v = cre(v2 + vb2[e*32 + o2]);

    const int i32 = l & 31;
    const int srcl = (i32 < 16) ? (4*i32) : (4*(i32-16)+1);
    const float h2full = __shfl(h2v, srcl);
    float pv = vW3[e*32 + i32] * h2full;
    pv += __shfl_xor(pv, 1); pv += __shfl_xor(pv, 2); pv += __shfl_xor(pv, 4);
    pv += __shfl_xor(pv, 8); pv += __shfl_xor(pv, 16);
    if (l == 0) out0[b] = tanhf(pv + vb3[e] + psqt);

    const int sf = 4 + 4*g + (l&3);
    const int st = sf + 16;
    float4 xpf, xpt;
    xpf.x = __shfl(embv.x, sf); xpf.y = __shfl(embv.y, sf);
    xpf.z = __shfl(embv.z, sf); xpf.w = __shfl(embv.w, sf);
    xpt.x = __shfl(embv.x, st); xpt.y = __shfl(embv.y, st);
    xpt.z = __shfl(embv.z, st); xpt.w = __shfl(embv.w, st);
    float apf[4], apt[4];
    #pragma unroll
    for (int k=0;k<4;k++){
        const float4 wfk = *reinterpret_cast<const float4*>(pfW + e*1024 + k*256 + l*4);
        const float4 wtk = *reinterpret_cast<const float4*>(ptW + e*1024 + k*256 + l*4);
        apf[k] = wfk.x*xpf.x + wfk.y*xpf.y + wfk.z*xpf.z + wfk.w*xpf.w;
        apt[k] = wtk.x*xpt.x + wtk.y*xpt.y + wtk.z*xpt.z + wtk.w*xpt.w;
    }
    #pragma unroll
    for (int i=0;i<2;i++){
        float give = (l&1) ? apf[2*i] : apf[2*i+1];
        float keep = (l&1) ? apf[2*i+1] : apf[2*i];
        apf[i] = keep + __shfl_xor(give, 1);
        give = (l&1) ? apt[2*i] : apt[2*i+1];
        keep = (l&1) ? apt[2*i+1] : apt[2*i];
        apt[i] = keep + __shfl_xor(give, 1);
    }
    float pfv, ptv;
    {
        float give = ((l>>1)&1) ? apf[0] : apf[1];
        float keep = ((l>>1)&1) ? apf[1] : apf[0];
        pfv = keep + __shfl_xor(give, 2);
        give = ((l>>1)&1) ? apt[0] : apt[1];
        keep = ((l>>1)&1) ? apt[1] : apt[0];
        ptv = keep + __shfl_xor(give, 2);
    }
    const int o = ((l&3)<<4) + (l>>2);
    out1[b*64 + o] = pfv + pfb[e*64 + o];
    out2[b*64 + o] = ptv + ptb[e*64 + o];
}

extern "C" void kernel_launch(void* const* d_in, const int* in_sizes, int n_in,
                              void* d_out, int out_size, void* d_ws, size_t ws_size,
                              hipStream_t stream) {
    const int*   indices = (const int*)d_in[0];
    const int*   offsets = (const int*)d_in[1];
    const int*   which   = (const int*)d_in[2];
    const float* embed   = (const float*)d_in[4];
    const float* mbias   = (const float*)d_in[5];
    const float* vW1 = (const float*)d_in[6];
    const float* vb1 = (const float*)d_in[7];
    const float* vW2 = (const float*)d_in[8];
    const float* vb2 = (const float*)d_in[9];
    const float* vW3 = (const float*)d_in[10];
    const float* vb3 = (const float*)d_in[11];
    const float* pfW = (const float*)d_in[12];
    const float* pfb = (const float*)d_in[13];
    const float* ptW = (const float*)d_in[14];
    const float* ptb = (const float*)d_in[15];
    float* out0 = (float*)d_out;
    float* out1 = out0 + NB;
    float* out2 = out1 + (size_t)NB*64;

    const size_t tab_bytes  = (size_t)FEATC * 256;          // 27,262,976
    const size_t pk_bytes   = (size_t)NB * 128 * 4;         //  8,388,608
    const size_t list_bytes = 32 * 1024 * sizeof(int);
    const size_t need = tab_bytes + pk_bytes + list_bytes + 128;

    if (ws_size >= need) {
        unsigned char* tab = (unsigned char*)d_ws;
        unsigned int*  pk  = (unsigned int*)((unsigned char*)d_ws + tab_bytes);
        int* list = (int*)((unsigned char*)d_ws + tab_bytes + pk_bytes);
        int* cnt  = list + 32*1024;

        hipMemsetAsync(pk, 0, pk_bytes, stream);
        k0_group<<<32, 256, 0, stream>>>(which, list, cnt);
        convert_i8<<<2048, 256, 0, stream>>>(embed, (unsigned int*)tab, FEATC*64);
        k2_range<<<(NB/8)*8, 512, 0, stream>>>(indices, offsets, tab, pk);
        k3_tail<<<32*32, 256, 0, stream>>>(list, cnt, pk, mbias,
            vW1, vb1, vW2, vb2, vW3, vb3, pfW, pfb, ptW, ptb, out0, out1, out2);
    } else {
        nnue_fused_f<<<NB/4, 256, 0, stream>>>(indices, offsets, which, embed, mbias,
            vW1, vb1, vW2, vb2, vW3, vb3, pfW, pfb, ptW, ptb, out0, out1, out2);
    }
}

// Round 12
// 83.043 us; speedup vs baseline: 1.8928x; 1.8928x over previous
//
#include <hip/hip_runtime.h>

#define NB 16384
#define FEATC 106496
#define MSPLIT 2732              // samples handled by fp32 path inside kA (4*683)
#define QSCALE (1.0f/2048.0f)
#define QINV   2048.0f

typedef float f32x4 __attribute__((ext_vector_type(4)));

#define SB() __builtin_amdgcn_sched_barrier(0)

__device__ __forceinline__ float cre(float x){
    float c = fminf(fmaxf(x, 0.0f), 127.0f/128.0f);
    return c + 0.1f*(x-c);
}

// ---------------- shared MLP tail (post-accumulate) ----------------
__device__ __forceinline__ void mlp_tail(
    float4 embv, float psqt, int e, int g, int l, int b,
    const float* __restrict__ vW1, const float* __restrict__ vb1,
    const float* __restrict__ vW2, const float* __restrict__ vb2,
    const float* __restrict__ vW3, const float* __restrict__ vb3,
    const float* __restrict__ pfW, const float* __restrict__ pfb,
    const float* __restrict__ ptW, const float* __restrict__ ptb,
    float* __restrict__ out0, float* __restrict__ out1, float* __restrict__ out2)
{
    float a1[16];
    {
        const float* w1 = vW1 + e*4096;
        float4 w[8], w2[8];
        #pragma unroll
        for (int k=0;k<8;k++)
            w[k] = *reinterpret_cast<const float4*>(w1 + k*256 + l*4);
        SB();
        #pragma unroll
        for (int k=0;k<8;k++)
            w2[k] = *reinterpret_cast<const float4*>(w1 + (8+k)*256 + l*4);
        SB();
        #pragma unroll
        for (int k=0;k<8;k++)
            a1[k] = w[k].x*embv.x + w[k].y*embv.y + w[k].z*embv.z + w[k].w*embv.w;
        SB();
        #pragma unroll
        for (int k=0;k<8;k++)
            a1[8+k] = w2[k].x*embv.x + w2[k].y*embv.y + w2[k].z*embv.z + w2[k].w*embv.w;
    }
    #pragma unroll
    for (int i=0;i<8;i++){
        float give = (l&1) ? a1[2*i] : a1[2*i+1];
        float keep = (l&1) ? a1[2*i+1] : a1[2*i];
        a1[i] = keep + __shfl_xor(give, 1);
    }
    #pragma unroll
    for (int i=0;i<4;i++){
        float give = ((l>>1)&1) ? a1[2*i] : a1[2*i+1];
        float keep = ((l>>1)&1) ? a1[2*i+1] : a1[2*i];
        a1[i] = keep + __shfl_xor(give, 2);
    }
    #pragma unroll
    for (int i=0;i<2;i++){
        float give = ((l>>2)&1) ? a1[2*i] : a1[2*i+1];
        float keep = ((l>>2)&1) ? a1[2*i+1] : a1[2*i];
        a1[i] = keep + __shfl_xor(give, 4);
    }
    {
        float give = ((l>>3)&1) ? a1[0] : a1[1];
        float keep = ((l>>3)&1) ? a1[1] : a1[0];
        a1[0] = keep + __shfl_xor(give, 8);
    }
    a1[0] += __shfl_xor(a1[0], 16);
    a1[0] += __shfl_xor(a1[0], 32);
    const float h1v = cre(a1[0] + vb1[e*16 + (l&15)]);

    float4 w2a, w2b, wf[4], wt[4];
    w2a = *reinterpret_cast<const float4*>(vW2 + e*512 + l*4);
    w2b = *reinterpret_cast<const float4*>(vW2 + e*512 + 256 + l*4);
    #pragma unroll
    for (int k=0;k<4;k++){
        wf[k] = *reinterpret_cast<const float4*>(pfW + e*1024 + k*256 + l*4);
        wt[k] = *reinterpret_cast<const float4*>(ptW + e*1024 + k*256 + l*4);
    }
    SB();

    float4 xh1;
    xh1.x = __shfl(h1v, (l&3)*4 + 0);
    xh1.y = __shfl(h1v, (l&3)*4 + 1);
    xh1.z = __shfl(h1v, (l&3)*4 + 2);
    xh1.w = __shfl(h1v, (l&3)*4 + 3);
    float a2[2];
    a2[0] = w2a.x*xh1.x + w2a.y*xh1.y + w2a.z*xh1.z + w2a.w*xh1.w;
    a2[1] = w2b.x*xh1.x + w2b.y*xh1.y + w2b.z*xh1.z + w2b.w*xh1.w;
    float v2;
    {
        float give = (l&1) ? a2[0] : a2[1];
        float keep = (l&1) ? a2[1] : a2[0];
        v2 = keep + __shfl_xor(give, 1);
        v2 += __shfl_xor(v2, 2);
    }
    const int o2 = ((l&1)<<4) + (l>>2);
    const float h2v = cre(v2 + vb2[e*32 + o2]);

    const int i32 = l & 31;
    const int srcl = (i32 < 16) ? (4*i32) : (4*(i32-16)+1);
    const float h2full = __shfl(h2v, srcl);
    float pv = vW3[e*32 + i32] * h2full;
    pv += __shfl_xor(pv, 1); pv += __shfl_xor(pv, 2); pv += __shfl_xor(pv, 4);
    pv += __shfl_xor(pv, 8); pv += __shfl_xor(pv, 16);
    if (l == 0) out0[b] = tanhf(pv + vb3[e] + psqt);

    const int sf = 4 + 4*g + (l&3);
    const int st = sf + 16;
    float4 xpf, xpt;
    xpf.x = __shfl(embv.x, sf); xpf.y = __shfl(embv.y, sf);
    xpf.z = __shfl(embv.z, sf); xpf.w = __shfl(embv.w, sf);
    xpt.x = __shfl(embv.x, st); xpt.y = __shfl(embv.y, st);
    xpt.z = __shfl(embv.z, st); xpt.w = __shfl(embv.w, st);
    float apf[4], apt[4];
    #pragma unroll
    for (int k=0;k<4;k++){
        apf[k] = wf[k].x*xpf.x + wf[k].y*xpf.y + wf[k].z*xpf.z + wf[k].w*xpf.w;
        apt[k] = wt[k].x*xpt.x + wt[k].y*xpt.y + wt[k].z*xpt.z + wt[k].w*xpt.w;
    }
    #pragma unroll
    for (int i=0;i<2;i++){
        float give = (l&1) ? apf[2*i] : apf[2*i+1];
        float keep = (l&1) ? apf[2*i+1] : apf[2*i];
        apf[i] = keep + __shfl_xor(give, 1);
        give = (l&1) ? apt[2*i] : apt[2*i+1];
        keep = (l&1) ? apt[2*i+1] : apt[2*i];
        apt[i] = keep + __shfl_xor(give, 1);
    }
    float pfv, ptv;
    {
        float give = ((l>>1)&1) ? apf[0] : apf[1];
        float keep = ((l>>1)&1) ? apf[1] : apf[0];
        pfv = keep + __shfl_xor(give, 2);
        give = ((l>>1)&1) ? apt[0] : apt[1];
        keep = ((l>>1)&1) ? apt[1] : apt[0];
        ptv = keep + __shfl_xor(give, 2);
    }
    const int o = ((l&3)<<4) + (l>>2);
    out1[b*64 + o] = pfv + pfb[e*64 + o];
    out2[b*64 + o] = ptv + ptb[e*64 + o];
}

// ---- fp32 gather body (exact math; used for overlapped samples & fallback) ----
__device__ __forceinline__ void gather_f32_and_tail(
    int b, int l,
    const int* __restrict__ indices, const int* __restrict__ offsets,
    const int* __restrict__ which_model,
    const float* __restrict__ embed, const float* __restrict__ main_bias,
    const float* __restrict__ vW1, const float* __restrict__ vb1,
    const float* __restrict__ vW2, const float* __restrict__ vb2,
    const float* __restrict__ vW3, const float* __restrict__ vb3,
    const float* __restrict__ pfW, const float* __restrict__ pfb,
    const float* __restrict__ ptW, const float* __restrict__ ptb,
    float* __restrict__ out0, float* __restrict__ out1, float* __restrict__ out2)
{
    const int e    = __builtin_amdgcn_readfirstlane(which_model[b]);
    const int base = __builtin_amdgcn_readfirstlane(offsets[b]);
    const int g    = e >> 3;

    const int4* ip = reinterpret_cast<const int4*>(indices + base);
    int4 r0 = ip[0], r1 = ip[1], r2 = ip[2], r3 = ip[3];
    int4 r4 = ip[4], r5 = ip[5], r6 = ip[6], r7 = ip[7];
    int rows[32] = {r0.x,r0.y,r0.z,r0.w, r1.x,r1.y,r1.z,r1.w,
                    r2.x,r2.y,r2.z,r2.w, r3.x,r3.y,r3.z,r3.w,
                    r4.x,r4.y,r4.z,r4.w, r5.x,r5.y,r5.z,r5.w,
                    r6.x,r6.y,r6.z,r6.w, r7.x,r7.y,r7.z,r7.w};

    float4 va[8], vb_[8];
    float4 acc = *reinterpret_cast<const float4*>(main_bias + l*4);
    #pragma unroll
    for (int j=0;j<8;j++)
        va[j] = *reinterpret_cast<const float4*>(embed + (size_t)rows[j]*256 + l*4);
    SB();
    #pragma unroll
    for (int j=0;j<8;j++)
        vb_[j] = *reinterpret_cast<const float4*>(embed + (size_t)rows[8+j]*256 + l*4);
    SB();
    #pragma unroll
    for (int j=0;j<8;j++){ acc.x+=va[j].x; acc.y+=va[j].y; acc.z+=va[j].z; acc.w+=va[j].w; }
    SB();
    #pragma unroll
    for (int j=0;j<8;j++)
        va[j] = *reinterpret_cast<const float4*>(embed + (size_t)rows[16+j]*256 + l*4);
    SB();
    #pragma unroll
    for (int j=0;j<8;j++){ acc.x+=vb_[j].x; acc.y+=vb_[j].y; acc.z+=vb_[j].z; acc.w+=vb_[j].w; }
    SB();
    #pragma unroll
    for (int j=0;j<8;j++)
        vb_[j] = *reinterpret_cast<const float4*>(embed + (size_t)rows[24+j]*256 + l*4);
    SB();
    #pragma unroll
    for (int j=0;j<8;j++){ acc.x+=va[j].x; acc.y+=va[j].y; acc.z+=va[j].z; acc.w+=va[j].w; }
    SB();
    #pragma unroll
    for (int j=0;j<8;j++){ acc.x+=vb_[j].x; acc.y+=vb_[j].y; acc.z+=vb_[j].z; acc.w+=vb_[j].w; }

    const float psqt = __shfl(acc.x, 0);
    float4 embv;
    embv.x = cre(acc.x); embv.y = cre(acc.y); embv.z = cre(acc.z); embv.w = cre(acc.w);

    mlp_tail(embv, psqt, e, g, l, b, vW1, vb1, vW2, vb2, vW3, vb3,
             pfW, pfb, ptW, ptb, out0, out1, out2);
}

// ---------------- K_A: convert (3/4 of blocks) ∥ fp32 gather (1/4 of blocks) ----------
__global__ __launch_bounds__(256, 4) void kA_mix(
    const float* __restrict__ embed, unsigned int* __restrict__ tab4,
    const int* __restrict__ indices, const int* __restrict__ offsets,
    const int* __restrict__ which_model, const float* __restrict__ main_bias,
    const float* __restrict__ vW1, const float* __restrict__ vb1,
    const float* __restrict__ vW2, const float* __restrict__ vb2,
    const float* __restrict__ vW3, const float* __restrict__ vb3,
    const float* __restrict__ pfW, const float* __restrict__ pfb,
    const float* __restrict__ ptW, const float* __restrict__ ptb,
    float* __restrict__ out0, float* __restrict__ out1, float* __restrict__ out2)
{
    const int bid = blockIdx.x;
    if ((bid & 3) != 3){
        // convert chunk c in [0,2048)
        const int c = (bid >> 2)*3 + (bid & 3);
        if (c >= 2048) return;
        const int n4 = FEATC*64;
        for (int i = c*256 + (int)threadIdx.x; i < n4; i += 2048*256){
            const f32x4* sp = reinterpret_cast<const f32x4*>(embed) + i;
            f32x4 v = __builtin_nontemporal_load(sp);
            int a = __float2int_rn(fminf(fmaxf(v.x*QINV, -127.0f), 127.0f));
            int b = __float2int_rn(fminf(fmaxf(v.y*QINV, -127.0f), 127.0f));
            int cc= __float2int_rn(fminf(fmaxf(v.z*QINV, -127.0f), 127.0f));
            int d = __float2int_rn(fminf(fmaxf(v.w*QINV, -127.0f), 127.0f));
            tab4[i] = (a & 0xff) | ((b & 0xff) << 8) | ((cc & 0xff) << 16) | ((d & 0xff) << 24);
        }
        return;
    }
    // fp32 gather for samples [0, MSPLIT)
    const int q  = bid >> 2;
    const int l  = threadIdx.x & 63;
    const int wv = (int)threadIdx.x >> 6;
    const int b  = q*4 + wv;
    gather_f32_and_tail(b, l, indices, offsets, which_model, embed, main_bias,
                        vW1, vb1, vW2, vb2, vW3, vb3, pfW, pfb, ptW, ptb,
                        out0, out1, out2);
}

// ---------------- K_B: int8 fused gather for samples [MSPLIT, NB) ----------------
__global__ __launch_bounds__(256, 4) void kB_q(
    const int* __restrict__ indices,
    const int* __restrict__ offsets,
    const int* __restrict__ which_model,
    const unsigned char* __restrict__ tab,
    const float* __restrict__ main_bias,
    const float* __restrict__ vW1, const float* __restrict__ vb1,
    const float* __restrict__ vW2, const float* __restrict__ vb2,
    const float* __restrict__ vW3, const float* __restrict__ vb3,
    const float* __restrict__ pfW, const float* __restrict__ pfb,
    const float* __restrict__ ptW, const float* __restrict__ ptb,
    float* __restrict__ out0, float* __restrict__ out1, float* __restrict__ out2)
{
    const int tid = threadIdx.x;
    const int l  = tid & 63;
    const int wv = tid >> 6;
    const int b  = MSPLIT + (blockIdx.x << 2) + wv;

    const int e    = __builtin_amdgcn_readfirstlane(which_model[b]);
    const int base = __builtin_amdgcn_readfirstlane(offsets[b]);
    const int g    = e >> 3;

    const int4* ip = reinterpret_cast<const int4*>(indices + base);
    int4 r0 = ip[0], r1 = ip[1], r2 = ip[2], r3 = ip[3];
    int4 r4 = ip[4], r5 = ip[5], r6 = ip[6], r7 = ip[7];
    int rows[32] = {r0.x,r0.y,r0.z,r0.w, r1.x,r1.y,r1.z,r1.w,
                    r2.x,r2.y,r2.z,r2.w, r3.x,r3.y,r3.z,r3.w,
                    r4.x,r4.y,r4.z,r4.w, r5.x,r5.y,r5.z,r5.w,
                    r6.x,r6.y,r6.z,r6.w, r7.x,r7.y,r7.z,r7.w};

    int s0=0, s1=0, s2=0, s3=0;
    unsigned int va[8], vb[8], vc[8];
    #pragma unroll
    for (int j=0;j<8;j++)
        va[j] = *reinterpret_cast<const unsigned int*>(tab + (size_t)rows[j]*256 + l*4);
    SB();
    #pragma unroll
    for (int j=0;j<8;j++)
        vb[j] = *reinterpret_cast<const unsigned int*>(tab + (size_t)rows[8+j]*256 + l*4);
    SB();
    #pragma unroll
    for (int j=0;j<8;j++)
        vc[j] = *reinterpret_cast<const unsigned int*>(tab + (size_t)rows[16+j]*256 + l*4);
    SB();
    #pragma unroll
    for (int j=0;j<8;j++){
        unsigned int w = va[j];
        s0 += (int)(w << 24) >> 24;
        s1 += (int)(w << 16) >> 24;
        s2 += (int)(w <<  8) >> 24;
        s3 += (int)w >> 24;
    }
    SB();
    #pragma unroll
    for (int j=0;j<8;j++)
        va[j] = *reinterpret_cast<const unsigned int*>(tab + (size_t)rows[24+j]*256 + l*4);
    SB();
    #pragma unroll
    for (int j=0;j<8;j++){
        unsigned int w = vb[j];
        s0 += (int)(w << 24) >> 24;
        s1 += (int)(w << 16) >> 24;
        s2 += (int)(w <<  8) >> 24;
        s3 += (int)w >> 24;
    }
    #pragma unroll
    for (int j=0;j<8;j++){
        unsigned int w = vc[j];
        s0 += (int)(w << 24) >> 24;
        s1 += (int)(w << 16) >> 24;
        s2 += (int)(w <<  8) >> 24;
        s3 += (int)w >> 24;
    }
    #pragma unroll
    for (int j=0;j<8;j++){
        unsigned int w = va[j];
        s0 += (int)(w << 24) >> 24;
        s1 += (int)(w << 16) >> 24;
        s2 += (int)(w <<  8) >> 24;
        s3 += (int)w >> 24;
    }

    const float4 bias = *reinterpret_cast<const float4*>(main_bias + l*4);
    float4 acc;
    acc.x = (float)s0 * QSCALE + bias.x;
    acc.y = (float)s1 * QSCALE + bias.y;
    acc.z = (float)s2 * QSCALE + bias.z;
    acc.w = (float)s3 * QSCALE + bias.w;

    const float psqt = __shfl(acc.x, 0);
    float4 embv;
    embv.x = cre(acc.x); embv.y = cre(acc.y); embv.z = cre(acc.z); embv.w = cre(acc.w);

    mlp_tail(embv, psqt, e, g, l, b, vW1, vb1, vW2, vb2, vW3, vb3,
             pfW, pfb, ptW, ptb, out0, out1, out2);
}

// ---------------- fallback: pure fp32 monolithic over all samples ----------------
__global__ __launch_bounds__(256, 4) void nnue_fused_f(
    const int* __restrict__ indices,
    const int* __restrict__ offsets,
    const int* __restrict__ which_model,
    const float* __restrict__ embed,
    const float* __restrict__ main_bias,
    const float* __restrict__ vW1, const float* __restrict__ vb1,
    const float* __restrict__ vW2, const float* __restrict__ vb2,
    const float* __restrict__ vW3, const float* __restrict__ vb3,
    const float* __restrict__ pfW, const float* __restrict__ pfb,
    const float* __restrict__ ptW, const float* __restrict__ ptb,
    float* __restrict__ out0, float* __restrict__ out1, float* __restrict__ out2)
{
    const int tid = threadIdx.x;
    const int l  = tid & 63;
    const int wv = tid >> 6;
    const int b  = (blockIdx.x << 2) + wv;
    gather_f32_and_tail(b, l, indices, offsets, which_model, embed, main_bias,
                        vW1, vb1, vW2, vb2, vW3, vb3, pfW, pfb, ptW, ptb,
                        out0, out1, out2);
}

extern "C" void kernel_launch(void* const* d_in, const int* in_sizes, int n_in,
                              void* d_out, int out_size, void* d_ws, size_t ws_size,
                              hipStream_t stream) {
    const int*   indices = (const int*)d_in[0];
    const int*   offsets = (const int*)d_in[1];
    const int*   which   = (const int*)d_in[2];
    const float* embed   = (const float*)d_in[4];
    const float* mbias   = (const float*)d_in[5];
    const float* vW1 = (const float*)d_in[6];
    const float* vb1 = (const float*)d_in[7];
    const float* vW2 = (const float*)d_in[8];
    const float* vb2 = (const float*)d_in[9];
    const float* vW3 = (const float*)d_in[10];
    const float* vb3 = (const float*)d_in[11];
    const float* pfW = (const float*)d_in[12];
    const float* pfb = (const float*)d_in[13];
    const float* ptW = (const float*)d_in[14];
    const float* ptb = (const float*)d_in[15];
    float* out0 = (float*)d_out;
    float* out1 = out0 + NB;
    float* out2 = out1 + (size_t)NB*64;

    const size_t need = (size_t)FEATC * 256;
    if (ws_size >= need) {
        unsigned char* tab = (unsigned char*)d_ws;
        // K_A: 2732 blocks = 2048 convert chunks (bid&3!=3) + 683 fp32-gather blocks
        kA_mix<<<MSPLIT, 256, 0, stream>>>(embed, (unsigned int*)tab,
            indices, offsets, which, mbias,
            vW1, vb1, vW2, vb2, vW3, vb3, pfW, pfb, ptW, ptb, out0, out1, out2);
        // K_B: int8 fused for remaining samples
        kB_q<<<(NB - MSPLIT)/4, 256, 0, stream>>>(indices, offsets, which, tab, mbias,
            vW1, vb1, vW2, vb2, vW3, vb3, pfW, pfb, ptW, ptb, out0, out1, out2);
    } else {
        nnue_fused_f<<<NB/4, 256, 0, stream>>>(indices, offsets, which, embed, mbias,
            vW1, vb1, vW2, vb2, vW3, vb3, pfW, pfb, ptW, ptb, out0, out1, out2);
    }
}

// Round 13
// 56.274 us; speedup vs baseline: 2.7932x; 1.4757x over previous
//
#include <hip/hip_runtime.h>
#include <hip/hip_fp16.h>

#define NB 16384
#define FEATC 106496
#define NFEAT 32
#define QSCALE (1.0f/2048.0f)
#define QINV   2048.0f

__device__ __forceinline__ float cre(float x){
    float c = fminf(fmaxf(x, 0.0f), 127.0f/128.0f);
    return c + 0.1f*(x-c);
}

#define SB() __builtin_amdgcn_sched_barrier(0)

// ---------------- fp32 -> int8 (scale 2^-11) table conversion ----------------
__global__ __launch_bounds__(256) void convert_i8(
    const float4* __restrict__ src, unsigned int* __restrict__ dst, int n4)
{
    int i = blockIdx.x*blockDim.x + threadIdx.x;
    const int stride = gridDim.x*blockDim.x;
    for (; i < n4; i += stride){
        float4 v = src[i];
        int a = __float2int_rn(fminf(fmaxf(v.x*QINV, -127.0f), 127.0f));
        int b = __float2int_rn(fminf(fmaxf(v.y*QINV, -127.0f), 127.0f));
        int c = __float2int_rn(fminf(fmaxf(v.z*QINV, -127.0f), 127.0f));
        int d = __float2int_rn(fminf(fmaxf(v.w*QINV, -127.0f), 127.0f));
        dst[i] = (a & 0xff) | ((b & 0xff) << 8) | ((c & 0xff) << 16) | ((d & 0xff) << 24);
    }
}

// ---------------- shared MLP tail (post-accumulate) ----------------
__device__ __forceinline__ void mlp_tail(
    float4 embv, float psqt, int e, int g, int l, int b,
    const float* __restrict__ vW1, const float* __restrict__ vb1,
    const float* __restrict__ vW2, const float* __restrict__ vb2,
    const float* __restrict__ vW3, const float* __restrict__ vb3,
    const float* __restrict__ pfW, const float* __restrict__ pfb,
    const float* __restrict__ ptW, const float* __restrict__ ptb,
    float* __restrict__ out0, float* __restrict__ out1, float* __restrict__ out2)
{
    // ---- h1 = cre(vW1[e] @ emb + vb1[e]) : 16 outputs, K=256 ----
    float a1[16];
    {
        const float* w1 = vW1 + e*4096;
        float4 w[8], w2[8];
        #pragma unroll
        for (int k=0;k<8;k++)
            w[k] = *reinterpret_cast<const float4*>(w1 + k*256 + l*4);
        SB();
        #pragma unroll
        for (int k=0;k<8;k++)
            w2[k] = *reinterpret_cast<const float4*>(w1 + (8+k)*256 + l*4);
        SB();
        #pragma unroll
        for (int k=0;k<8;k++)
            a1[k] = w[k].x*embv.x + w[k].y*embv.y + w[k].z*embv.z + w[k].w*embv.w;
        SB();
        #pragma unroll
        for (int k=0;k<8;k++)
            a1[8+k] = w2[k].x*embv.x + w2[k].y*embv.y + w2[k].z*embv.z + w2[k].w*embv.w;
    }
    // merge-butterfly: lane l ends with h1[l&15]
    #pragma unroll
    for (int i=0;i<8;i++){
        float give = (l&1) ? a1[2*i] : a1[2*i+1];
        float keep = (l&1) ? a1[2*i+1] : a1[2*i];
        a1[i] = keep + __shfl_xor(give, 1);
    }
    #pragma unroll
    for (int i=0;i<4;i++){
        float give = ((l>>1)&1) ? a1[2*i] : a1[2*i+1];
        float keep = ((l>>1)&1) ? a1[2*i+1] : a1[2*i];
        a1[i] = keep + __shfl_xor(give, 2);
    }
    #pragma unroll
    for (int i=0;i<2;i++){
        float give = ((l>>2)&1) ? a1[2*i] : a1[2*i+1];
        float keep = ((l>>2)&1) ? a1[2*i+1] : a1[2*i];
        a1[i] = keep + __shfl_xor(give, 4);
    }
    {
        float give = ((l>>3)&1) ? a1[0] : a1[1];
        float keep = ((l>>3)&1) ? a1[1] : a1[0];
        a1[0] = keep + __shfl_xor(give, 8);
    }
    a1[0] += __shfl_xor(a1[0], 16);
    a1[0] += __shfl_xor(a1[0], 32);
    const float h1v = cre(a1[0] + vb1[e*16 + (l&15)]);   // lane l holds h1[l&15]

    // ---- issue all tail-layer weight loads together ----
    float4 w2a, w2b, wf[4], wt[4];
    w2a = *reinterpret_cast<const float4*>(vW2 + e*512 + l*4);
    w2b = *reinterpret_cast<const float4*>(vW2 + e*512 + 256 + l*4);
    #pragma unroll
    for (int k=0;k<4;k++){
        wf[k] = *reinterpret_cast<const float4*>(pfW + e*1024 + k*256 + l*4);
        wt[k] = *reinterpret_cast<const float4*>(ptW + e*1024 + k*256 + l*4);
    }
    SB();

    // ---- h2 : 32 outputs, K=16 ----
    float4 xh1;
    xh1.x = __shfl(h1v, (l&3)*4 + 0);
    xh1.y = __shfl(h1v, (l&3)*4 + 1);
    xh1.z = __shfl(h1v, (l&3)*4 + 2);
    xh1.w = __shfl(h1v, (l&3)*4 + 3);
    float a2[2];
    a2[0] = w2a.x*xh1.x + w2a.y*xh1.y + w2a.z*xh1.z + w2a.w*xh1.w;
    a2[1] = w2b.x*xh1.x + w2b.y*xh1.y + w2b.z*xh1.z + w2b.w*xh1.w;
    float v2;
    {
        float give = (l&1) ? a2[0] : a2[1];
        float keep = (l&1) ? a2[1] : a2[0];
        v2 = keep + __shfl_xor(give, 1);
        v2 += __shfl_xor(v2, 2);
    }
    const int o2 = ((l&1)<<4) + (l>>2);
    const float h2v = cre(v2 + vb2[e*32 + o2]);          // lane l holds h2[o2]

    // ---- value head ----
    const int i32 = l & 31;
    const int srcl = (i32 < 16) ? (4*i32) : (4*(i32-16)+1);
    const float h2full = __shfl(h2v, srcl);              // h2[l&31]
    float pv = vW3[e*32 + i32] * h2full;
    pv += __shfl_xor(pv, 1); pv += __shfl_xor(pv, 2); pv += __shfl_xor(pv, 4);
    pv += __shfl_xor(pv, 8); pv += __shfl_xor(pv, 16);
    if (l == 0) out0[b] = tanhf(pv + vb3[e] + psqt);

    // ---- policy heads ----
    const int sf = 4 + 4*g + (l&3);
    const int st = sf + 16;
    float4 xpf, xpt;
    xpf.x = __shfl(embv.x, sf); xpf.y = __shfl(embv.y, sf);
    xpf.z = __shfl(embv.z, sf); xpf.w = __shfl(embv.w, sf);
    xpt.x = __shfl(embv.x, st); xpt.y = __shfl(embv.y, st);
    xpt.z = __shfl(embv.z, st); xpt.w = __shfl(embv.w, st);
    float apf[4], apt[4];
    #pragma unroll
    for (int k=0;k<4;k++){
        apf[k] = wf[k].x*xpf.x + wf[k].y*xpf.y + wf[k].z*xpf.z + wf[k].w*xpf.w;
        apt[k] = wt[k].x*xpt.x + wt[k].y*xpt.y + wt[k].z*xpt.z + wt[k].w*xpt.w;
    }
    #pragma unroll
    for (int i=0;i<2;i++){
        float give = (l&1) ? apf[2*i] : apf[2*i+1];
        float keep = (l&1) ? apf[2*i+1] : apf[2*i];
        apf[i] = keep + __shfl_xor(give, 1);
        give = (l&1) ? apt[2*i] : apt[2*i+1];
        keep = (l&1) ? apt[2*i+1] : apt[2*i];
        apt[i] = keep + __shfl_xor(give, 1);
    }
    float pfv, ptv;
    {
        float give = ((l>>1)&1) ? apf[0] : apf[1];
        float keep = ((l>>1)&1) ? apf[1] : apf[0];
        pfv = keep + __shfl_xor(give, 2);
        give = ((l>>1)&1) ? apt[0] : apt[1];
        keep = ((l>>1)&1) ? apt[1] : apt[0];
        ptv = keep + __shfl_xor(give, 2);
    }
    const int o = ((l&3)<<4) + (l>>2);
    out1[b*64 + o] = pfv + pfb[e*64 + o];
    out2[b*64 + o] = ptv + ptb[e*64 + o];
}

// ---------------- fused kernel, int8 table ----------------
__global__ __launch_bounds__(256, 4) void nnue_fused_q(
    const int* __restrict__ indices,
    const int* __restrict__ offsets,
    const int* __restrict__ which_model,
    const unsigned char* __restrict__ tab,
    const float* __restrict__ main_bias,
    const float* __restrict__ vW1, const float* __restrict__ vb1,
    const float* __restrict__ vW2, const float* __restrict__ vb2,
    const float* __restrict__ vW3, const float* __restrict__ vb3,
    const float* __restrict__ pfW, const float* __restrict__ pfb,
    const float* __restrict__ ptW, const float* __restrict__ ptb,
    float* __restrict__ out0, float* __restrict__ out1, float* __restrict__ out2)
{
    const int tid = threadIdx.x;
    const int l  = tid & 63;
    const int wv = tid >> 6;
    const int b  = (blockIdx.x << 2) + wv;

    const int e    = __builtin_amdgcn_readfirstlane(which_model[b]);
    const int base = __builtin_amdgcn_readfirstlane(offsets[b]);
    const int g    = e >> 3;

    const int4* ip = reinterpret_cast<const int4*>(indices + base);
    int4 r0 = ip[0], r1 = ip[1], r2 = ip[2], r3 = ip[3];
    int4 r4 = ip[4], r5 = ip[5], r6 = ip[6], r7 = ip[7];
    int rows[32] = {r0.x,r0.y,r0.z,r0.w, r1.x,r1.y,r1.z,r1.w,
                    r2.x,r2.y,r2.z,r2.w, r3.x,r3.y,r3.z,r3.w,
                    r4.x,r4.y,r4.z,r4.w, r5.x,r5.y,r5.z,r5.w,
                    r6.x,r6.y,r6.z,r6.w, r7.x,r7.y,r7.z,r7.w};

    // ---- gather-accumulate on int8 rows (4 B/lane), exact int32 accum ----
    int s0=0, s1=0, s2=0, s3=0;
    unsigned int va[8], vb[8], vc[8];
    #pragma unroll
    for (int j=0;j<8;j++)
        va[j] = *reinterpret_cast<const unsigned int*>(tab + (size_t)rows[j]*256 + l*4);
    SB();
    #pragma unroll
    for (int j=0;j<8;j++)
        vb[j] = *reinterpret_cast<const unsigned int*>(tab + (size_t)rows[8+j]*256 + l*4);
    SB();
    #pragma unroll
    for (int j=0;j<8;j++)
        vc[j] = *reinterpret_cast<const unsigned int*>(tab + (size_t)rows[16+j]*256 + l*4);
    SB();
    #pragma unroll
    for (int j=0;j<8;j++){
        unsigned int w = va[j];
        s0 += (int)(w << 24) >> 24;
        s1 += (int)(w << 16) >> 24;
        s2 += (int)(w <<  8) >> 24;
        s3 += (int)w >> 24;
    }
    SB();
    #pragma unroll
    for (int j=0;j<8;j++)
        va[j] = *reinterpret_cast<const unsigned int*>(tab + (size_t)rows[24+j]*256 + l*4);
    SB();
    #pragma unroll
    for (int j=0;j<8;j++){
        unsigned int w = vb[j];
        s0 += (int)(w << 24) >> 24;
        s1 += (int)(w << 16) >> 24;
        s2 += (int)(w <<  8) >> 24;
        s3 += (int)w >> 24;
    }
    #pragma unroll
    for (int j=0;j<8;j++){
        unsigned int w = vc[j];
        s0 += (int)(w << 24) >> 24;
        s1 += (int)(w << 16) >> 24;
        s2 += (int)(w <<  8) >> 24;
        s3 += (int)w >> 24;
    }
    #pragma unroll
    for (int j=0;j<8;j++){
        unsigned int w = va[j];
        s0 += (int)(w << 24) >> 24;
        s1 += (int)(w << 16) >> 24;
        s2 += (int)(w <<  8) >> 24;
        s3 += (int)w >> 24;
    }

    const float4 bias = *reinterpret_cast<const float4*>(main_bias + l*4);
    float4 acc;
    acc.x = (float)s0 * QSCALE + bias.x;
    acc.y = (float)s1 * QSCALE + bias.y;
    acc.z = (float)s2 * QSCALE + bias.z;
    acc.w = (float)s3 * QSCALE + bias.w;

    const float psqt = __shfl(acc.x, 0);
    float4 embv;
    embv.x = cre(acc.x); embv.y = cre(acc.y); embv.z = cre(acc.z); embv.w = cre(acc.w);

    mlp_tail(embv, psqt, e, g, l, b, vW1, vb1, vW2, vb2, vW3, vb3,
             pfW, pfb, ptW, ptb, out0, out1, out2);
}

// ---------------- fallback: fp32 table (round-3 path) ----------------
__global__ __launch_bounds__(256, 4) void nnue_fused_f(
    const int* __restrict__ indices,
    const int* __restrict__ offsets,
    const int* __restrict__ which_model,
    const float* __restrict__ embed,
    const float* __restrict__ main_bias,
    const float* __restrict__ vW1, const float* __restrict__ vb1,
    const float* __restrict__ vW2, const float* __restrict__ vb2,
    const float* __restrict__ vW3, const float* __restrict__ vb3,
    const float* __restrict__ pfW, const float* __restrict__ pfb,
    const float* __restrict__ ptW, const float* __restrict__ ptb,
    float* __restrict__ out0, float* __restrict__ out1, float* __restrict__ out2)
{
    const int tid = threadIdx.x;
    const int l  = tid & 63;
    const int wv = tid >> 6;
    const int b  = (blockIdx.x << 2) + wv;

    const int e    = __builtin_amdgcn_readfirstlane(which_model[b]);
    const int base = __builtin_amdgcn_readfirstlane(offsets[b]);
    const int g    = e >> 3;

    const int4* ip = reinterpret_cast<const int4*>(indices + base);
    int4 r0 = ip[0], r1 = ip[1], r2 = ip[2], r3 = ip[3];
    int4 r4 = ip[4], r5 = ip[5], r6 = ip[6], r7 = ip[7];
    int rows[32] = {r0.x,r0.y,r0.z,r0.w, r1.x,r1.y,r1.z,r1.w,
                    r2.x,r2.y,r2.z,r2.w, r3.x,r3.y,r3.z,r3.w,
                    r4.x,r4.y,r4.z,r4.w, r5.x,r5.y,r5.z,r5.w,
                    r6.x,r6.y,r6.z,r6.w, r7.x,r7.y,r7.z,r7.w};

    float4 va[8], vb[8];
    float4 acc = *reinterpret_cast<const float4*>(main_bias + l*4);
    #pragma unroll
    for (int j=0;j<8;j++)
        va[j] = *reinterpret_cast<const float4*>(embed + (size_t)rows[j]*256 + l*4);
    SB();
    #pragma unroll
    for (int j=0;j<8;j++)
        vb[j] = *reinterpret_cast<const float4*>(embed + (size_t)rows[8+j]*256 + l*4);
    SB();
    #pragma unroll
    for (int j=0;j<8;j++){ acc.x+=va[j].x; acc.y+=va[j].y; acc.z+=va[j].z; acc.w+=va[j].w; }
    SB();
    #pragma unroll
    for (int j=0;j<8;j++)
        va[j] = *reinterpret_cast<const float4*>(embed + (size_t)rows[16+j]*256 + l*4);
    SB();
    #pragma unroll
    for (int j=0;j<8;j++){ acc.x+=vb[j].x; acc.y+=vb[j].y; acc.z+=vb[j].z; acc.w+=vb[j].w; }
    SB();
    #pragma unroll
    for (int j=0;j<8;j++)
        vb[j] = *reinterpret_cast<const float4*>(embed + (size_t)rows[24+j]*256 + l*4);
    SB();
    #pragma unroll
    for (int j=0;j<8;j++){ acc.x+=va[j].x; acc.y+=va[j].y; acc.z+=va[j].z; acc.w+=va[j].w; }
    SB();
    #pragma unroll
    for (int j=0;j<8;j++){ acc.x+=vb[j].x; acc.y+=vb[j].y; acc.z+=vb[j].z; acc.w+=vb[j].w; }

    const float psqt = __shfl(acc.x, 0);
    float4 embv;
    embv.x = cre(acc.x); embv.y = cre(acc.y); embv.z = cre(acc.z); embv.w = cre(acc.w);

    mlp_tail(embv, psqt, e, g, l, b, vW1, vb1, vW2, vb2, vW3, vb3,
             pfW, pfb, ptW, ptb, out0, out1, out2);
}

extern "C" void kernel_launch(void* const* d_in, const int* in_sizes, int n_in,
                              void* d_out, int out_size, void* d_ws, size_t ws_size,
                              hipStream_t stream) {
    const int*   indices = (const int*)d_in[0];
    const int*   offsets = (const int*)d_in[1];
    const int*   which   = (const int*)d_in[2];
    const float* embed   = (const float*)d_in[4];
    const float* mbias   = (const float*)d_in[5];
    const float* vW1 = (const float*)d_in[6];
    const float* vb1 = (const float*)d_in[7];
    const float* vW2 = (const float*)d_in[8];
    const float* vb2 = (const float*)d_in[9];
    const float* vW3 = (const float*)d_in[10];
    const float* vb3 = (const float*)d_in[11];
    const float* pfW = (const float*)d_in[12];
    const float* pfb = (const float*)d_in[13];
    const float* ptW = (const float*)d_in[14];
    const float* ptb = (const float*)d_in[15];
    float* out0 = (float*)d_out;
    float* out1 = out0 + NB;
    float* out2 = out1 + (size_t)NB*64;

    const size_t need = (size_t)FEATC * 256;
    if (ws_size >= need) {
        unsigned char* tab = (unsigned char*)d_ws;
        const int n4 = FEATC * 256 / 4;
        convert_i8<<<2048, 256, 0, stream>>>(
            reinterpret_cast<const float4*>(embed), reinterpret_cast<unsigned int*>(tab), n4);
        nnue_fused_q<<<NB/4, 256, 0, stream>>>(indices, offsets, which, tab, mbias,
            vW1, vb1, vW2, vb2, vW3, vb3, pfW, pfb, ptW, ptb, out0, out1, out2);
    } else {
        nnue_fused_f<<<NB/4, 256, 0, stream>>>(indices, offsets, which, embed, mbias,
            vW1, vb1, vW2, vb2, vW3, vb3, pfW, pfb, ptW, ptb, out0, out1, out2);
    }
}